// Round 10
// baseline (226.549 us; speedup 1.0000x reference)
//
#include <hip/hip_runtime.h>

constexpr int N_NODES  = 100000;
constexpr int N_EDGES  = 3200000;
constexpr int N_GRAPHS = 64;
constexpr int HALF_N   = 50000;                          // src-half split for L2 blocking

constexpr int BSHIFT   = 8;                              // 256 nodes per bin
constexpr int NBINS    = (N_NODES + 255) >> BSHIFT;      // 391
constexpr int BIN_CAP  = 9216;                           // mean 8184, +11 sigma
constexpr int SRC_BITS = 17;                             // 100000 < 2^17
constexpr int SRC_MASK = (1 << SRC_BITS) - 1;

constexpr int NB_BIN = 500;                              // ~2 blocks/CU
constexpr int EPB    = N_EDGES / NB_BIN;                 // 6400 (exact)
constexpr int EPT    = (EPB + 1023) / 1024;              // 7

typedef float v4f __attribute__((ext_vector_type(4)));

// ================= CSR build: block-local LDS counting sort =================

__global__ __launch_bounds__(1024) void bin_kernel(
        const int* __restrict__ src, const int* __restrict__ dst,
        int* __restrict__ bin_cur, int* __restrict__ binned) {
    __shared__ int pk[EPB];                 // packed (ln<<17)|src, load order
    __shared__ unsigned short bn[EPB];      // bin id, load order
    __shared__ unsigned short ord[EPB];     // sorted pos -> load index
    __shared__ int hist[NBINS];
    __shared__ int lexcl[NBINS];
    __shared__ int lofs[NBINS];
    __shared__ int gofs[NBINS];
    __shared__ int s512[512];
    int tid = threadIdx.x;
    int e0 = blockIdx.x * EPB;
    for (int i = tid; i < NBINS; i += 1024) hist[i] = 0;
    __syncthreads();
#pragma unroll
    for (int k = 0; k < EPT; ++k) {
        int i = tid + k * 1024;
        if (i < EPB) {
            int d = __builtin_nontemporal_load(&dst[e0 + i]);
            int s = __builtin_nontemporal_load(&src[e0 + i]);
            int b = d >> BSHIFT;
            pk[i] = ((d & 255) << SRC_BITS) | s;
            bn[i] = (unsigned short)b;
            atomicAdd(&hist[b], 1);
        }
    }
    __syncthreads();
    if (tid < 512) s512[tid] = (tid < NBINS) ? hist[tid] : 0;
    __syncthreads();
    for (int o = 1; o < 512; o <<= 1) {
        int x = 0;
        if (tid < 512 && tid >= o) x = s512[tid - o];
        __syncthreads();
        if (tid < 512) s512[tid] += x;
        __syncthreads();
    }
    if (tid < NBINS) {
        int h = hist[tid];
        int excl = s512[tid] - h;
        lexcl[tid] = excl;
        lofs[tid]  = excl;
        gofs[tid]  = h ? atomicAdd(&bin_cur[tid], h) : 0;
    }
    __syncthreads();
#pragma unroll
    for (int k = 0; k < EPT; ++k) {
        int i = tid + k * 1024;
        if (i < EPB) {
            int r = atomicAdd(&lofs[bn[i]], 1);
            ord[r] = (unsigned short)i;
        }
    }
    __syncthreads();
#pragma unroll
    for (int k = 0; k < EPT; ++k) {
        int i = tid + k * 1024;
        if (i < EPB) {
            int j = ord[i];
            int b = bn[j];
            int pos = gofs[b] + (i - lexcl[b]);
            if (pos < BIN_CAP)
                __builtin_nontemporal_store(pk[j], &binned[(size_t)b * BIN_CAP + pos]);
        }
    }
}

__global__ void binscan_kernel(const int* __restrict__ bin_cur, int* __restrict__ bin_base,
                               int* __restrict__ rowptr) {
    __shared__ int s[512];
    int t = threadIdx.x;
    int v = (t < NBINS) ? bin_cur[t] : 0;
    s[t] = v;
    __syncthreads();
    for (int o = 1; o < 512; o <<= 1) {
        int x = (t >= o) ? s[t - o] : 0;
        __syncthreads();
        s[t] += x;
        __syncthreads();
    }
    if (t < NBINS) bin_base[t] = s[t] - v;
    if (t == 0) rowptr[N_NODES] = N_EDGES;
}

// One block per 256-node bin. Rows stored [src<H | src>=H]; rowmid = boundary.
__global__ __launch_bounds__(1024) void csrbuild_kernel(
        const int* __restrict__ binned, const int* __restrict__ bin_cur,
        const int* __restrict__ bin_base, int* __restrict__ rowptr,
        int* __restrict__ rowmid, float* __restrict__ dis, int* __restrict__ csr) {
    __shared__ int cnt[512];                 // idx = (ln<<1)|half
    __shared__ int lofs[512];
    __shared__ int s[512];
    int b = blockIdx.x;
    int t = threadIdx.x;
    int size  = min(bin_cur[b], BIN_CAP);
    int gbase = bin_base[b];
    const int* bp = binned + (size_t)b * BIN_CAP;
    if (t < 512) cnt[t] = 0;
    __syncthreads();
    int pc[9];                                   // 9*1024 >= BIN_CAP
#pragma unroll
    for (int k = 0; k < 9; ++k) {
        int i = t + k * 1024;
        pc[k] = (i < size) ? __builtin_nontemporal_load(&bp[i]) : -1;
        if (i < size) {
            int p = pc[k];
            int idx = ((p >> SRC_BITS) << 1) | ((p & SRC_MASK) >= HALF_N);
            atomicAdd(&cnt[idx], 1);
        }
    }
    __syncthreads();
    if (t < 512) s[t] = cnt[t];
    __syncthreads();
    for (int o = 1; o < 512; o <<= 1) {
        int x = 0;
        if (t < 512 && t >= o) x = s[t - o];
        __syncthreads();
        if (t < 512) s[t] += x;
        __syncthreads();
    }
    if (t < 512) lofs[t] = s[t] - cnt[t];
    __syncthreads();                             // lofs ready; cnt still valid
    if (t < 256) {
        int n = (b << BSHIFT) + t;
        if (n < N_NODES) {
            int deg = cnt[2 * t] + cnt[2 * t + 1];
            dis[n] = 1.0f / sqrtf((float)deg + 1.0f);  // +1 self loop
            rowptr[n] = gbase + lofs[2 * t];
            rowmid[n] = gbase + lofs[2 * t + 1];
        }
    }
    __syncthreads();                             // all reads of cnt done
    if (t < 512) cnt[t] = 0;
    __syncthreads();
#pragma unroll
    for (int k = 0; k < 9; ++k) {
        int i = t + k * 1024;
        if (i < size) {
            int p = pc[k];
            int srcv = p & SRC_MASK;
            int idx = ((p >> SRC_BITS) << 1) | (srcv >= HALF_N);
            int r = atomicAdd(&cnt[idx], 1);
            csr[gbase + lofs[idx] + r] = srcv;
        }
    }
}

// ================= per-layer kernels =================

__global__ void pre1_kernel(const float* __restrict__ x, const float* __restrict__ dis,
                            float* __restrict__ xs) {
    int i = blockIdx.x * blockDim.x + threadIdx.x;
    if (i >= N_NODES) return;
    float d = dis[i];
    float4 v;
    v.x = __builtin_nontemporal_load(&x[(size_t)i * 3 + 0]) * d;
    v.y = __builtin_nontemporal_load(&x[(size_t)i * 3 + 1]) * d;
    v.z = __builtin_nontemporal_load(&x[(size_t)i * 3 + 2]) * d;
    v.w = 0.f;
    *reinterpret_cast<float4*>(&xs[(size_t)i * 4]) = v;
}

// MLP-deep gather: G=4 lanes/node, lane owns VPL=F/4 features; 8-edge unroll.
template<int F, bool ADD_B, bool RELU>
__global__ __launch_bounds__(256) void gather_kernel(
        const float* __restrict__ in, const int* __restrict__ rowptr,
        const int* __restrict__ csr, const float* __restrict__ dis,
        const float* __restrict__ b, float* __restrict__ out) {
    constexpr int G   = 4;
    constexpr int VPL = F / G;
    constexpr int NPB = 256 / G;
    int tid  = threadIdx.x;
    int lane = tid & (G - 1);
    int n    = blockIdx.x * NPB + (tid >> 2);
    if (n >= N_NODES) return;
    int beg = rowptr[n], end = rowptr[n + 1];
    const float* ip = in + (size_t)lane * VPL;
    float a0[VPL], a1[VPL], a2[VPL], a3[VPL];
#pragma unroll
    for (int j = 0; j < VPL; ++j) {
        a0[j] = ip[(size_t)n * F + j];      // self loop (already dis-scaled)
        a1[j] = 0.f; a2[j] = 0.f; a3[j] = 0.f;
    }
    int k = beg;
    for (; k + 7 < end; k += 8) {
        int s0 = __builtin_nontemporal_load(&csr[k + 0]);
        int s1 = __builtin_nontemporal_load(&csr[k + 1]);
        int s2 = __builtin_nontemporal_load(&csr[k + 2]);
        int s3 = __builtin_nontemporal_load(&csr[k + 3]);
        int s4 = __builtin_nontemporal_load(&csr[k + 4]);
        int s5 = __builtin_nontemporal_load(&csr[k + 5]);
        int s6 = __builtin_nontemporal_load(&csr[k + 6]);
        int s7 = __builtin_nontemporal_load(&csr[k + 7]);
        const float* r0 = &ip[(size_t)s0 * F];
        const float* r1 = &ip[(size_t)s1 * F];
        const float* r2 = &ip[(size_t)s2 * F];
        const float* r3 = &ip[(size_t)s3 * F];
        const float* r4 = &ip[(size_t)s4 * F];
        const float* r5 = &ip[(size_t)s5 * F];
        const float* r6 = &ip[(size_t)s6 * F];
        const float* r7 = &ip[(size_t)s7 * F];
#pragma unroll
        for (int j = 0; j < VPL; ++j) a0[j] += r0[j];
#pragma unroll
        for (int j = 0; j < VPL; ++j) a1[j] += r1[j];
#pragma unroll
        for (int j = 0; j < VPL; ++j) a2[j] += r2[j];
#pragma unroll
        for (int j = 0; j < VPL; ++j) a3[j] += r3[j];
#pragma unroll
        for (int j = 0; j < VPL; ++j) a0[j] += r4[j];
#pragma unroll
        for (int j = 0; j < VPL; ++j) a1[j] += r5[j];
#pragma unroll
        for (int j = 0; j < VPL; ++j) a2[j] += r6[j];
#pragma unroll
        for (int j = 0; j < VPL; ++j) a3[j] += r7[j];
    }
    for (; k < end; ++k) {
        int s0 = __builtin_nontemporal_load(&csr[k]);
        const float* r0 = &ip[(size_t)s0 * F];
#pragma unroll
        for (int j = 0; j < VPL; ++j) a0[j] += r0[j];
    }
    float d = dis[n];
#pragma unroll
    for (int j = 0; j < VPL; ++j) {
        float v = ((a0[j] + a1[j]) + (a2[j] + a3[j])) * d;
        if (ADD_B) v += b[lane * VPL + j];
        if (RELU) v = fmaxf(v, 0.f);
        __builtin_nontemporal_store(v, &out[(size_t)n * F + lane * VPL + j]);
    }
}

// Layer-2 gather, src-half blocked. PHASE 0: [rowptr,rowmid), partial sums.
// PHASE 1: [rowmid,rowptr+1) + partial + epilogue. Operand half fits XCD L2.
template<int PHASE>
__global__ __launch_bounds__(256) void gather16_kernel(
        const float* __restrict__ in, const int* __restrict__ rowptr,
        const int* __restrict__ rowmid, const int* __restrict__ csr,
        const float* __restrict__ dis, const float* __restrict__ b,
        float* __restrict__ out) {
    constexpr int F = 16, VPL = 4;
    int tid  = threadIdx.x;
    int lane = tid & 3;
    int n    = blockIdx.x * 64 + (tid >> 2);
    if (n >= N_NODES) return;
    int beg = (PHASE == 0) ? rowptr[n] : rowmid[n];
    int end = (PHASE == 0) ? rowmid[n] : rowptr[n + 1];
    const float* ip = in + (size_t)lane * VPL;
    float a0[4], a1[4], a2[4], a3[4];
#pragma unroll
    for (int j = 0; j < 4; ++j) { a0[j] = 0.f; a1[j] = 0.f; a2[j] = 0.f; a3[j] = 0.f; }
    if (PHASE == 0) {
        if (n < HALF_N) {
#pragma unroll
            for (int j = 0; j < 4; ++j) a0[j] = ip[(size_t)n * F + j];  // self in this half
        }
    } else {
        v4f pv = __builtin_nontemporal_load(
            reinterpret_cast<const v4f*>(&out[(size_t)n * F + lane * 4]));
        a0[0] = pv.x; a0[1] = pv.y; a0[2] = pv.z; a0[3] = pv.w;
        if (n >= HALF_N) {
#pragma unroll
            for (int j = 0; j < 4; ++j) a1[j] = ip[(size_t)n * F + j];
        }
    }
    int k = beg;
    for (; k + 7 < end; k += 8) {
        int s0 = __builtin_nontemporal_load(&csr[k + 0]);
        int s1 = __builtin_nontemporal_load(&csr[k + 1]);
        int s2 = __builtin_nontemporal_load(&csr[k + 2]);
        int s3 = __builtin_nontemporal_load(&csr[k + 3]);
        int s4 = __builtin_nontemporal_load(&csr[k + 4]);
        int s5 = __builtin_nontemporal_load(&csr[k + 5]);
        int s6 = __builtin_nontemporal_load(&csr[k + 6]);
        int s7 = __builtin_nontemporal_load(&csr[k + 7]);
        const float* r0 = &ip[(size_t)s0 * F];
        const float* r1 = &ip[(size_t)s1 * F];
        const float* r2 = &ip[(size_t)s2 * F];
        const float* r3 = &ip[(size_t)s3 * F];
        const float* r4 = &ip[(size_t)s4 * F];
        const float* r5 = &ip[(size_t)s5 * F];
        const float* r6 = &ip[(size_t)s6 * F];
        const float* r7 = &ip[(size_t)s7 * F];
#pragma unroll
        for (int j = 0; j < 4; ++j) a0[j] += r0[j];
#pragma unroll
        for (int j = 0; j < 4; ++j) a1[j] += r1[j];
#pragma unroll
        for (int j = 0; j < 4; ++j) a2[j] += r2[j];
#pragma unroll
        for (int j = 0; j < 4; ++j) a3[j] += r3[j];
#pragma unroll
        for (int j = 0; j < 4; ++j) a0[j] += r4[j];
#pragma unroll
        for (int j = 0; j < 4; ++j) a1[j] += r5[j];
#pragma unroll
        for (int j = 0; j < 4; ++j) a2[j] += r6[j];
#pragma unroll
        for (int j = 0; j < 4; ++j) a3[j] += r7[j];
    }
    for (; k < end; ++k) {
        int s0 = __builtin_nontemporal_load(&csr[k]);
        const float* r0 = &ip[(size_t)s0 * F];
#pragma unroll
        for (int j = 0; j < 4; ++j) a0[j] += r0[j];
    }
    v4f v;
    if (PHASE == 0) {
        v.x = (a0[0] + a1[0]) + (a2[0] + a3[0]);
        v.y = (a0[1] + a1[1]) + (a2[1] + a3[1]);
        v.z = (a0[2] + a1[2]) + (a2[2] + a3[2]);
        v.w = (a0[3] + a1[3]) + (a2[3] + a3[3]);
    } else {
        float d = dis[n];
        const float* bb = b + lane * 4;
        v.x = fmaxf(((a0[0] + a1[0]) + (a2[0] + a3[0])) * d + bb[0], 0.f);
        v.y = fmaxf(((a0[1] + a1[1]) + (a2[1] + a3[1])) * d + bb[1], 0.f);
        v.z = fmaxf(((a0[2] + a1[2]) + (a2[2] + a3[2])) * d + bb[2], 0.f);
        v.w = fmaxf(((a0[3] + a1[3]) + (a2[3] + a3[3])) * d + bb[3], 0.f);
    }
    __builtin_nontemporal_store(v, reinterpret_cast<v4f*>(&out[(size_t)n * F + lane * 4]));
}

// h1[i,f] = relu( m[i,:]@W1 + b1 )
__global__ void lin1_kernel(const float* __restrict__ m, const float* __restrict__ W1,
                            const float* __restrict__ b1, float* __restrict__ h1) {
    int i = blockIdx.x * blockDim.x + threadIdx.x;
    if (i >= N_NODES) return;
    float4 mv = *reinterpret_cast<const float4*>(&m[(size_t)i * 4]);
#pragma unroll
    for (int f = 0; f < 32; ++f) {
        float s = b1[f];
        s = fmaf(mv.x, W1[0 * 32 + f], s);
        s = fmaf(mv.y, W1[1 * 32 + f], s);
        s = fmaf(mv.z, W1[2 * 32 + f], s);
        h1[(size_t)i * 32 + f] = fmaxf(s, 0.f);
    }
}

// g[i,:FOUT] = (in[i,:FIN] @ W) * dis[i]; input NT-read (dead after)
template<int FIN, int FOUT>
__global__ void lin_pre_kernel(const float* __restrict__ in, const float* __restrict__ W,
                               const float* __restrict__ dis, float* __restrict__ g) {
    int i = blockIdx.x * blockDim.x + threadIdx.x;
    if (i >= N_NODES) return;
    float xin[FIN];
    const v4f* hp = reinterpret_cast<const v4f*>(&in[(size_t)i * FIN]);
#pragma unroll
    for (int q = 0; q < FIN / 4; ++q) {
        v4f v = __builtin_nontemporal_load(&hp[q]);
        xin[q * 4 + 0] = v.x; xin[q * 4 + 1] = v.y;
        xin[q * 4 + 2] = v.z; xin[q * 4 + 3] = v.w;
    }
    float d = dis[i];
#pragma unroll
    for (int f = 0; f < FOUT; ++f) {
        float s = 0.f;
#pragma unroll
        for (int k = 0; k < FIN; ++k) s = fmaf(xin[k], W[k * FOUT + f], s);
        g[(size_t)i * FOUT + f] = s * d;
    }
}

// ================= pooling + final linear =================

__global__ void pool_kernel(const float* __restrict__ h, const int* __restrict__ batch,
                            float* __restrict__ pool) {
    __shared__ float lsum[N_GRAPHS * 8];
    __shared__ float lcnt[N_GRAPHS];
    int tid = threadIdx.x;
    for (int j = tid; j < N_GRAPHS * 8; j += blockDim.x) lsum[j] = 0.f;
    for (int j = tid; j < N_GRAPHS; j += blockDim.x) lcnt[j] = 0.f;
    __syncthreads();
    int i = blockIdx.x * blockDim.x + tid;
    if (i < N_NODES) {
        int gm = batch[i];
        const float4* hp = reinterpret_cast<const float4*>(&h[(size_t)i * 8]);
        float4 a = hp[0], bq = hp[1];
        atomicAdd(&lsum[gm * 8 + 0], a.x);
        atomicAdd(&lsum[gm * 8 + 1], a.y);
        atomicAdd(&lsum[gm * 8 + 2], a.z);
        atomicAdd(&lsum[gm * 8 + 3], a.w);
        atomicAdd(&lsum[gm * 8 + 4], bq.x);
        atomicAdd(&lsum[gm * 8 + 5], bq.y);
        atomicAdd(&lsum[gm * 8 + 6], bq.z);
        atomicAdd(&lsum[gm * 8 + 7], bq.w);
        atomicAdd(&lcnt[gm], 1.0f);
    }
    __syncthreads();
    for (int idx = tid; idx < N_GRAPHS * 9; idx += blockDim.x) {
        int gm = idx / 9, j = idx % 9;
        if (lcnt[gm] != 0.f) {
            if (j < 8) atomicAdd(&pool[gm * 8 + j], lsum[gm * 8 + j]);
            else       atomicAdd(&pool[512 + gm], lcnt[gm]);
        }
    }
}

__global__ void final_kernel(const float* __restrict__ pool, const float* __restrict__ Wf,
                             const float* __restrict__ bf, float* __restrict__ out) {
    int t = threadIdx.x;
    if (t >= N_GRAPHS * 3) return;
    int gm = t / 3, c = t % 3;
    float cnt = fmaxf(pool[512 + gm], 1.0f);
    float s = 0.f;
#pragma unroll
    for (int f = 0; f < 8; ++f) s = fmaf(pool[gm * 8 + f] / cnt, Wf[f * 3 + c], s);
    out[t] = s + bf[c];
}

// ================= launch =================

extern "C" void kernel_launch(void* const* d_in, const int* in_sizes, int n_in,
                              void* d_out, int out_size, void* d_ws, size_t ws_size,
                              hipStream_t stream) {
    const float* x     = (const float*)d_in[0];
    const int*   ei    = (const int*)d_in[1];
    const int*   batch = (const int*)d_in[2];
    const float* W1 = (const float*)d_in[3];
    const float* b1 = (const float*)d_in[4];
    const float* W2 = (const float*)d_in[5];
    const float* b2 = (const float*)d_in[6];
    const float* W3 = (const float*)d_in[7];
    const float* b3 = (const float*)d_in[8];
    const float* Wf = (const float*)d_in[9];
    const float* bf = (const float*)d_in[10];

    const int* src = ei;              // edge_index[0] = message sources
    const int* dst = ei + N_EDGES;    // edge_index[1] = aggregation targets

    const int N = N_NODES, E = N_EDGES;

    // workspace layout; binned (36N ints) aliases the activation region (72N)
    // liveness (units of N floats within act):
    //   L1: xs[0,4) -> m[4,8) -> h1[8,40)
    //   L2: h1[8,40) -> g[40,56) -> h2[56,72) (partial then final, same thread)
    //   L3: h2[56,72) -> g8[0,8) -> h3[8,16) -> pool
    int*   bin_cur  = (int*)d_ws;                         // NBINS
    int*   bin_base = bin_cur + NBINS;                    // NBINS
    int*   rowptr   = bin_base + NBINS;                   // N+2
    int*   rowmid   = rowptr + (N + 2);                   // N
    float* dis      = (float*)(rowmid + N);               // N
    int*   csr      = (int*)(dis + N);                    // E
    float* act      = (float*)(csr + E);                  // 72N floats
    int*   binned   = (int*)act;
    float* xs   = act;                                    // 4N
    float* m    = act + (size_t)4  * N;                   // 4N
    float* h1   = act + (size_t)8  * N;                   // 32N
    float* g    = act + (size_t)40 * N;                   // 16N
    float* h2   = act + (size_t)56 * N;                   // 16N
    float* pool = act + (size_t)72 * N;                   // 576
    float* g8   = act;                                    // 8N  [0,8)   (xs,m dead)
    float* h3   = act + (size_t)8 * N;                    // 8N  [8,16)  (h1 dead)

    const int B = 256;
    const int NB_N = (N + B - 1) / B;
    const int NB_G = (N + 63) / 64;   // gather grids: 64 nodes/block

    hipMemsetAsync(bin_cur, 0, NBINS * sizeof(int), stream);
    hipMemsetAsync(pool, 0, N_GRAPHS * 9 * sizeof(float), stream);

    // CSR build (rows split [src<H | src>=H], rowmid = boundary)
    bin_kernel<<<NB_BIN, 1024, 0, stream>>>(src, dst, bin_cur, binned);
    binscan_kernel<<<1, 512, 0, stream>>>(bin_cur, bin_base, rowptr);
    csrbuild_kernel<<<NBINS, 1024, 0, stream>>>(binned, bin_cur, bin_base, rowptr, rowmid, dis, csr);

    // Layer 1: aggregate in padded 3-dim input space, then 4->32 linear
    pre1_kernel<<<NB_N, B, 0, stream>>>(x, dis, xs);
    gather_kernel<4, false, false><<<NB_G, B, 0, stream>>>(xs, rowptr, csr, dis, b1, m);
    lin1_kernel<<<NB_N, B, 0, stream>>>(m, W1, b1, h1);

    // Layer 2: 32->16 linear (*dis), src-half-blocked 16-wide gather
    lin_pre_kernel<32, 16><<<NB_N, B, 0, stream>>>(h1, W2, dis, g);
    gather16_kernel<0><<<NB_G, B, 0, stream>>>(g, rowptr, rowmid, csr, dis, b2, h2);
    gather16_kernel<1><<<NB_G, B, 0, stream>>>(g, rowptr, rowmid, csr, dis, b2, h2);

    // Layer 3: 16->8 linear (*dis), 8-wide gather (+b3, relu)
    lin_pre_kernel<16, 8><<<NB_N, B, 0, stream>>>(h2, W3, dis, g8);
    gather_kernel<8, true, true><<<NB_G, B, 0, stream>>>(g8, rowptr, csr, dis, b3, h3);

    // Pool + final linear
    pool_kernel<<<NB_N, B, 0, stream>>>(h3, batch, pool);
    final_kernel<<<1, 256, 0, stream>>>(pool, Wf, bf, (float*)d_out);
}

// Round 11
// 199.542 us; speedup vs baseline: 1.1353x; 1.1353x over previous
//
#include <hip/hip_runtime.h>

constexpr int N_NODES  = 100000;
constexpr int N_EDGES  = 3200000;
constexpr int N_GRAPHS = 64;

constexpr int BSHIFT   = 8;                              // 256 nodes per bin
constexpr int NBINS    = (N_NODES + 255) >> BSHIFT;      // 391
constexpr int BIN_CAP  = 9216;                           // mean 8184, +11 sigma
constexpr int SRC_BITS = 17;                             // 100000 < 2^17
constexpr int SRC_MASK = (1 << SRC_BITS) - 1;

constexpr int NB_BIN = 500;                              // ~2 blocks/CU
constexpr int EPB    = N_EDGES / NB_BIN;                 // 6400 (exact)
constexpr int EPT    = (EPB + 1023) / 1024;              // 7

typedef float v4f __attribute__((ext_vector_type(4)));

// ================= CSR build: block-local LDS counting sort =================

__global__ __launch_bounds__(1024) void bin_kernel(
        const int* __restrict__ src, const int* __restrict__ dst,
        int* __restrict__ bin_cur, int* __restrict__ binned) {
    __shared__ int pk[EPB];                 // packed (ln<<17)|src, load order
    __shared__ unsigned short bn[EPB];      // bin id, load order
    __shared__ unsigned short ord[EPB];     // sorted pos -> load index
    __shared__ int hist[NBINS];
    __shared__ int lexcl[NBINS];
    __shared__ int lofs[NBINS];
    __shared__ int gofs[NBINS];
    __shared__ int s512[512];
    int tid = threadIdx.x;
    int e0 = blockIdx.x * EPB;
    for (int i = tid; i < NBINS; i += 1024) hist[i] = 0;
    __syncthreads();
#pragma unroll
    for (int k = 0; k < EPT; ++k) {
        int i = tid + k * 1024;
        if (i < EPB) {
            int d = __builtin_nontemporal_load(&dst[e0 + i]);
            int s = __builtin_nontemporal_load(&src[e0 + i]);
            int b = d >> BSHIFT;
            pk[i] = ((d & 255) << SRC_BITS) | s;
            bn[i] = (unsigned short)b;
            atomicAdd(&hist[b], 1);
        }
    }
    __syncthreads();
    if (tid < 512) s512[tid] = (tid < NBINS) ? hist[tid] : 0;
    __syncthreads();
    for (int o = 1; o < 512; o <<= 1) {
        int x = 0;
        if (tid < 512 && tid >= o) x = s512[tid - o];
        __syncthreads();
        if (tid < 512) s512[tid] += x;
        __syncthreads();
    }
    if (tid < NBINS) {
        int h = hist[tid];
        int excl = s512[tid] - h;
        lexcl[tid] = excl;
        lofs[tid]  = excl;
        gofs[tid]  = h ? atomicAdd(&bin_cur[tid], h) : 0;
    }
    __syncthreads();
#pragma unroll
    for (int k = 0; k < EPT; ++k) {
        int i = tid + k * 1024;
        if (i < EPB) {
            int r = atomicAdd(&lofs[bn[i]], 1);
            ord[r] = (unsigned short)i;
        }
    }
    __syncthreads();
#pragma unroll
    for (int k = 0; k < EPT; ++k) {
        int i = tid + k * 1024;
        if (i < EPB) {
            int j = ord[i];
            int b = bn[j];
            int pos = gofs[b] + (i - lexcl[b]);
            if (pos < BIN_CAP)
                __builtin_nontemporal_store(pk[j], &binned[(size_t)b * BIN_CAP + pos]);
        }
    }
}

__global__ void binscan_kernel(const int* __restrict__ bin_cur, int* __restrict__ bin_base,
                               int* __restrict__ rowptr) {
    __shared__ int s[512];
    int t = threadIdx.x;
    int v = (t < NBINS) ? bin_cur[t] : 0;
    s[t] = v;
    __syncthreads();
    for (int o = 1; o < 512; o <<= 1) {
        int x = (t >= o) ? s[t - o] : 0;
        __syncthreads();
        s[t] += x;
        __syncthreads();
    }
    if (t < NBINS) bin_base[t] = s[t] - v;
    if (t == 0) rowptr[N_NODES] = N_EDGES;
}

__global__ __launch_bounds__(1024) void csrbuild_kernel(
        const int* __restrict__ binned, const int* __restrict__ bin_cur,
        const int* __restrict__ bin_base, int* __restrict__ rowptr,
        float* __restrict__ dis, int* __restrict__ csr) {
    __shared__ int cnt[256];
    __shared__ int lofs[256];
    __shared__ int s[256];
    int b = blockIdx.x;
    int t = threadIdx.x;
    int size  = min(bin_cur[b], BIN_CAP);
    int gbase = bin_base[b];
    const int* bp = binned + (size_t)b * BIN_CAP;
    if (t < 256) cnt[t] = 0;
    __syncthreads();
    int pc[9];                                   // 9*1024 >= BIN_CAP
#pragma unroll
    for (int k = 0; k < 9; ++k) {
        int i = t + k * 1024;
        pc[k] = (i < size) ? __builtin_nontemporal_load(&bp[i]) : -1;
        if (i < size) atomicAdd(&cnt[pc[k] >> SRC_BITS], 1);
    }
    __syncthreads();
    if (t < 256) {
        int n = (b << BSHIFT) + t;
        int deg = cnt[t];
        if (n < N_NODES) dis[n] = 1.0f / sqrtf((float)deg + 1.0f);  // +1 self loop
        s[t] = deg;
    }
    __syncthreads();
    for (int o = 1; o < 256; o <<= 1) {
        int x = 0;
        if (t < 256 && t >= o) x = s[t - o];
        __syncthreads();
        if (t < 256) s[t] += x;
        __syncthreads();
    }
    if (t < 256) {
        int n = (b << BSHIFT) + t;
        int excl = s[t] - cnt[t];
        if (n < N_NODES) rowptr[n] = gbase + excl;
        lofs[t] = excl;
        cnt[t] = 0;
    }
    __syncthreads();
#pragma unroll
    for (int k = 0; k < 9; ++k) {
        int i = t + k * 1024;
        if (i < size) {
            int p = pc[k];
            int ln = p >> SRC_BITS;
            int r = atomicAdd(&cnt[ln], 1);
            csr[gbase + lofs[ln] + r] = p & SRC_MASK;
        }
    }
}

// ================= per-layer kernels =================

__global__ void pre1_kernel(const float* __restrict__ x, const float* __restrict__ dis,
                            float* __restrict__ xs) {
    int i = blockIdx.x * blockDim.x + threadIdx.x;
    if (i >= N_NODES) return;
    float d = dis[i];
    float4 v;
    v.x = __builtin_nontemporal_load(&x[(size_t)i * 3 + 0]) * d;
    v.y = __builtin_nontemporal_load(&x[(size_t)i * 3 + 1]) * d;
    v.z = __builtin_nontemporal_load(&x[(size_t)i * 3 + 2]) * d;
    v.w = 0.f;
    *reinterpret_cast<float4*>(&xs[(size_t)i * 4]) = v;
}

// Row-parallel gather: 16 lanes/node = 4 sublanes (features) x 4 quarters
// (edge-range split). Serial chain per thread ~deg/4; shfl_xor(4,8) combines.
template<int F, bool ADD_B, bool RELU>
__global__ __launch_bounds__(256) void gather_kernel(
        const float* __restrict__ in, const int* __restrict__ rowptr,
        const int* __restrict__ csr, const float* __restrict__ dis,
        const float* __restrict__ b, float* __restrict__ out) {
    constexpr int VPL = F / 4;          // features per sublane
    constexpr int NPB = 256 / 16;       // 16 nodes per block
    int tid  = threadIdx.x;
    int sub  = tid & 3;                 // feature sublane
    int qtr  = (tid >> 2) & 3;          // edge-range quarter
    int n    = blockIdx.x * NPB + (tid >> 4);
    if (n >= N_NODES) return;           // never taken: 6250*16 == N exactly
    int beg = rowptr[n], end = rowptr[n + 1];
    int len = end - beg;
    int kb = beg + ((len * qtr) >> 2);
    int ke = beg + ((len * (qtr + 1)) >> 2);
    const float* ip = in + (size_t)sub * VPL;
    float a0[VPL], a1[VPL], a2[VPL], a3[VPL];
#pragma unroll
    for (int j = 0; j < VPL; ++j) { a0[j] = 0.f; a1[j] = 0.f; a2[j] = 0.f; a3[j] = 0.f; }
    if (qtr == 0) {
#pragma unroll
        for (int j = 0; j < VPL; ++j) a0[j] = ip[(size_t)n * F + j];  // self loop
    }
    int k = kb;
    for (; k + 7 < ke; k += 8) {
        int s0 = __builtin_nontemporal_load(&csr[k + 0]);
        int s1 = __builtin_nontemporal_load(&csr[k + 1]);
        int s2 = __builtin_nontemporal_load(&csr[k + 2]);
        int s3 = __builtin_nontemporal_load(&csr[k + 3]);
        int s4 = __builtin_nontemporal_load(&csr[k + 4]);
        int s5 = __builtin_nontemporal_load(&csr[k + 5]);
        int s6 = __builtin_nontemporal_load(&csr[k + 6]);
        int s7 = __builtin_nontemporal_load(&csr[k + 7]);
        const float* r0 = &ip[(size_t)s0 * F];
        const float* r1 = &ip[(size_t)s1 * F];
        const float* r2 = &ip[(size_t)s2 * F];
        const float* r3 = &ip[(size_t)s3 * F];
        const float* r4 = &ip[(size_t)s4 * F];
        const float* r5 = &ip[(size_t)s5 * F];
        const float* r6 = &ip[(size_t)s6 * F];
        const float* r7 = &ip[(size_t)s7 * F];
#pragma unroll
        for (int j = 0; j < VPL; ++j) a0[j] += r0[j];
#pragma unroll
        for (int j = 0; j < VPL; ++j) a1[j] += r1[j];
#pragma unroll
        for (int j = 0; j < VPL; ++j) a2[j] += r2[j];
#pragma unroll
        for (int j = 0; j < VPL; ++j) a3[j] += r3[j];
#pragma unroll
        for (int j = 0; j < VPL; ++j) a0[j] += r4[j];
#pragma unroll
        for (int j = 0; j < VPL; ++j) a1[j] += r5[j];
#pragma unroll
        for (int j = 0; j < VPL; ++j) a2[j] += r6[j];
#pragma unroll
        for (int j = 0; j < VPL; ++j) a3[j] += r7[j];
    }
    if (k + 3 < ke) {
        int s0 = __builtin_nontemporal_load(&csr[k + 0]);
        int s1 = __builtin_nontemporal_load(&csr[k + 1]);
        int s2 = __builtin_nontemporal_load(&csr[k + 2]);
        int s3 = __builtin_nontemporal_load(&csr[k + 3]);
        const float* r0 = &ip[(size_t)s0 * F];
        const float* r1 = &ip[(size_t)s1 * F];
        const float* r2 = &ip[(size_t)s2 * F];
        const float* r3 = &ip[(size_t)s3 * F];
#pragma unroll
        for (int j = 0; j < VPL; ++j) a0[j] += r0[j];
#pragma unroll
        for (int j = 0; j < VPL; ++j) a1[j] += r1[j];
#pragma unroll
        for (int j = 0; j < VPL; ++j) a2[j] += r2[j];
#pragma unroll
        for (int j = 0; j < VPL; ++j) a3[j] += r3[j];
        k += 4;
    }
    for (; k < ke; ++k) {
        int s0 = __builtin_nontemporal_load(&csr[k]);
        const float* r0 = &ip[(size_t)s0 * F];
#pragma unroll
        for (int j = 0; j < VPL; ++j) a0[j] += r0[j];
    }
    float v[VPL];
#pragma unroll
    for (int j = 0; j < VPL; ++j) v[j] = (a0[j] + a1[j]) + (a2[j] + a3[j]);
    // combine quarters: lanes differing in bits 2,3 of lane id hold same (n,sub)
#pragma unroll
    for (int j = 0; j < VPL; ++j) v[j] += __shfl_xor(v[j], 4);
#pragma unroll
    for (int j = 0; j < VPL; ++j) v[j] += __shfl_xor(v[j], 8);
    if (qtr == 0) {
        float d = dis[n];
#pragma unroll
        for (int j = 0; j < VPL; ++j) {
            float w = v[j] * d;
            if (ADD_B) w += b[sub * VPL + j];
            if (RELU) w = fmaxf(w, 0.f);
            __builtin_nontemporal_store(w, &out[(size_t)n * F + sub * VPL + j]);
        }
    }
}

// h1[i,f] = relu( m[i,:]@W1 + b1 )
__global__ void lin1_kernel(const float* __restrict__ m, const float* __restrict__ W1,
                            const float* __restrict__ b1, float* __restrict__ h1) {
    int i = blockIdx.x * blockDim.x + threadIdx.x;
    if (i >= N_NODES) return;
    float4 mv = *reinterpret_cast<const float4*>(&m[(size_t)i * 4]);
#pragma unroll
    for (int f = 0; f < 32; ++f) {
        float s = b1[f];
        s = fmaf(mv.x, W1[0 * 32 + f], s);
        s = fmaf(mv.y, W1[1 * 32 + f], s);
        s = fmaf(mv.z, W1[2 * 32 + f], s);
        h1[(size_t)i * 32 + f] = fmaxf(s, 0.f);
    }
}

// g[i,:FOUT] = (in[i,:FIN] @ W) * dis[i]; input NT-read (dead after)
template<int FIN, int FOUT>
__global__ void lin_pre_kernel(const float* __restrict__ in, const float* __restrict__ W,
                               const float* __restrict__ dis, float* __restrict__ g) {
    int i = blockIdx.x * blockDim.x + threadIdx.x;
    if (i >= N_NODES) return;
    float xin[FIN];
    const v4f* hp = reinterpret_cast<const v4f*>(&in[(size_t)i * FIN]);
#pragma unroll
    for (int q = 0; q < FIN / 4; ++q) {
        v4f v = __builtin_nontemporal_load(&hp[q]);
        xin[q * 4 + 0] = v.x; xin[q * 4 + 1] = v.y;
        xin[q * 4 + 2] = v.z; xin[q * 4 + 3] = v.w;
    }
    float d = dis[i];
#pragma unroll
    for (int f = 0; f < FOUT; ++f) {
        float s = 0.f;
#pragma unroll
        for (int k = 0; k < FIN; ++k) s = fmaf(xin[k], W[k * FOUT + f], s);
        g[(size_t)i * FOUT + f] = s * d;
    }
}

// ================= pooling + final linear =================

__global__ void pool_kernel(const float* __restrict__ h, const int* __restrict__ batch,
                            float* __restrict__ pool) {
    __shared__ float lsum[N_GRAPHS * 8];
    __shared__ float lcnt[N_GRAPHS];
    int tid = threadIdx.x;
    for (int j = tid; j < N_GRAPHS * 8; j += blockDim.x) lsum[j] = 0.f;
    for (int j = tid; j < N_GRAPHS; j += blockDim.x) lcnt[j] = 0.f;
    __syncthreads();
    int i = blockIdx.x * blockDim.x + tid;
    if (i < N_NODES) {
        int gm = batch[i];
        const float4* hp = reinterpret_cast<const float4*>(&h[(size_t)i * 8]);
        float4 a = hp[0], bq = hp[1];
        atomicAdd(&lsum[gm * 8 + 0], a.x);
        atomicAdd(&lsum[gm * 8 + 1], a.y);
        atomicAdd(&lsum[gm * 8 + 2], a.z);
        atomicAdd(&lsum[gm * 8 + 3], a.w);
        atomicAdd(&lsum[gm * 8 + 4], bq.x);
        atomicAdd(&lsum[gm * 8 + 5], bq.y);
        atomicAdd(&lsum[gm * 8 + 6], bq.z);
        atomicAdd(&lsum[gm * 8 + 7], bq.w);
        atomicAdd(&lcnt[gm], 1.0f);
    }
    __syncthreads();
    for (int idx = tid; idx < N_GRAPHS * 9; idx += blockDim.x) {
        int gm = idx / 9, j = idx % 9;
        if (lcnt[gm] != 0.f) {
            if (j < 8) atomicAdd(&pool[gm * 8 + j], lsum[gm * 8 + j]);
            else       atomicAdd(&pool[512 + gm], lcnt[gm]);
        }
    }
}

__global__ void final_kernel(const float* __restrict__ pool, const float* __restrict__ Wf,
                             const float* __restrict__ bf, float* __restrict__ out) {
    int t = threadIdx.x;
    if (t >= N_GRAPHS * 3) return;
    int gm = t / 3, c = t % 3;
    float cnt = fmaxf(pool[512 + gm], 1.0f);
    float s = 0.f;
#pragma unroll
    for (int f = 0; f < 8; ++f) s = fmaf(pool[gm * 8 + f] / cnt, Wf[f * 3 + c], s);
    out[t] = s + bf[c];
}

// ================= launch =================

extern "C" void kernel_launch(void* const* d_in, const int* in_sizes, int n_in,
                              void* d_out, int out_size, void* d_ws, size_t ws_size,
                              hipStream_t stream) {
    const float* x     = (const float*)d_in[0];
    const int*   ei    = (const int*)d_in[1];
    const int*   batch = (const int*)d_in[2];
    const float* W1 = (const float*)d_in[3];
    const float* b1 = (const float*)d_in[4];
    const float* W2 = (const float*)d_in[5];
    const float* b2 = (const float*)d_in[6];
    const float* W3 = (const float*)d_in[7];
    const float* b3 = (const float*)d_in[8];
    const float* Wf = (const float*)d_in[9];
    const float* bf = (const float*)d_in[10];

    const int* src = ei;              // edge_index[0] = message sources
    const int* dst = ei + N_EDGES;    // edge_index[1] = aggregation targets

    const int N = N_NODES, E = N_EDGES;

    // workspace layout; binned (36N ints) aliases the activation region (72N)
    // liveness (units of N floats within act):
    //   L1: xs[0,4) -> m[4,8) -> h1[8,40)
    //   L2: h1[8,40) -> g[40,56) -> h2[56,72)
    //   L3: h2[56,72) -> g8[0,8) -> h3[8,16) -> pool
    int*   bin_cur  = (int*)d_ws;                         // NBINS
    int*   bin_base = bin_cur + NBINS;                    // NBINS
    int*   rowptr   = bin_base + NBINS;                   // N+2
    float* dis      = (float*)(rowptr + N + 2);           // N
    int*   csr      = (int*)(dis + N);                    // E
    float* act      = (float*)(csr + E);                  // 72N floats
    int*   binned   = (int*)act;
    float* xs   = act;                                    // 4N
    float* m    = act + (size_t)4  * N;                   // 4N
    float* h1   = act + (size_t)8  * N;                   // 32N
    float* g    = act + (size_t)40 * N;                   // 16N
    float* h2   = act + (size_t)56 * N;                   // 16N
    float* pool = act + (size_t)72 * N;                   // 576
    float* g8   = act;                                    // 8N  [0,8)   (xs,m dead)
    float* h3   = act + (size_t)8 * N;                    // 8N  [8,16)  (h1 dead)

    const int B = 256;
    const int NB_N = (N + B - 1) / B;
    const int NB_G = N / 16;          // 6250 blocks, 16 nodes each (exact)

    hipMemsetAsync(bin_cur, 0, NBINS * sizeof(int), stream);
    hipMemsetAsync(pool, 0, N_GRAPHS * 9 * sizeof(float), stream);

    // CSR build
    bin_kernel<<<NB_BIN, 1024, 0, stream>>>(src, dst, bin_cur, binned);
    binscan_kernel<<<1, 512, 0, stream>>>(bin_cur, bin_base, rowptr);
    csrbuild_kernel<<<NBINS, 1024, 0, stream>>>(binned, bin_cur, bin_base, rowptr, dis, csr);

    // Layer 1: aggregate in padded 3-dim input space, then 4->32 linear
    pre1_kernel<<<NB_N, B, 0, stream>>>(x, dis, xs);
    gather_kernel<4, false, false><<<NB_G, B, 0, stream>>>(xs, rowptr, csr, dis, b1, m);
    lin1_kernel<<<NB_N, B, 0, stream>>>(m, W1, b1, h1);

    // Layer 2: 32->16 linear (*dis), 16-wide row-parallel gather
    lin_pre_kernel<32, 16><<<NB_N, B, 0, stream>>>(h1, W2, dis, g);
    gather_kernel<16, true, true><<<NB_G, B, 0, stream>>>(g, rowptr, csr, dis, b2, h2);

    // Layer 3: 16->8 linear (*dis), 8-wide row-parallel gather
    lin_pre_kernel<16, 8><<<NB_N, B, 0, stream>>>(h2, W3, dis, g8);
    gather_kernel<8, true, true><<<NB_G, B, 0, stream>>>(g8, rowptr, csr, dis, b3, h3);

    // Pool + final linear
    pool_kernel<<<NB_N, B, 0, stream>>>(h3, batch, pool);
    final_kernel<<<1, 256, 0, stream>>>(pool, Wf, bf, (float*)d_out);
}